// Round 10
// baseline (2136.435 us; speedup 1.0000x reference)
//
#include <hip/hip_runtime.h>
#include <hip/hip_bf16.h>
#include <math.h>

typedef __attribute__((ext_vector_type(4))) float f32x4;
typedef __attribute__((ext_vector_type(8))) short bf16x8;

__device__ __forceinline__ unsigned short f2bf(float f) {
  unsigned int x = __builtin_bit_cast(unsigned int, f);
  x += 0x7fffu + ((x >> 16) & 1u);
  return (unsigned short)(x >> 16);
}
__device__ __forceinline__ float bf2f(unsigned short u) {
  unsigned int x = ((unsigned int)u) << 16;
  return __builtin_bit_cast(float, x);
}

__device__ __forceinline__ void gload_lds16(const void* g, void* l) {
  __builtin_amdgcn_global_load_lds(
      (const __attribute__((address_space(1))) unsigned int*)g,
      (__attribute__((address_space(3))) unsigned int*)l, 16, 0, 0);
}

// ---------------- fused f32 -> bf16 weight casts ----------------
__global__ void cvt_all(const float* __restrict__ s0, int n0, const float* __restrict__ s1, int n1,
                        const float* __restrict__ s2, int n2, const float* __restrict__ s3, int n3,
                        unsigned short* __restrict__ d) {
  int i = blockIdx.x * 256 + threadIdx.x;
  if (i >= n0 + n1 + n2 + n3) return;
  const float* s;
  int off;
  if (i < n0) { s = s0; off = 0; }
  else if (i < n0 + n1) { s = s1; off = n0; }
  else if (i < n0 + n1 + n2) { s = s2; off = n0 + n1; }
  else { s = s3; off = n0 + n1 + n2; }
  d[i] = f2bf(s[i - off]);
}

// ---------------- LayerNorm, f32 input (optional shift+window gather) ----------------
template <int REMAP>
__global__ __launch_bounds__(256)
void ln_kernel(const float* __restrict__ x, const float* __restrict__ g,
               const float* __restrict__ b, unsigned short* __restrict__ dst_o) {
  int r = blockIdx.x * 4 + (threadIdx.x >> 6);
  int lane = threadIdx.x & 63;
  size_t src;
  if (REMAP) {
    int w = r >> 6, t = r & 63;
    int bb = w >> 8, wi = (w >> 4) & 15, wj = w & 15;
    int i = t >> 3, j = t & 7;
    int p = (wi * 8 + i + 4) & 127, q = (wj * 8 + j + 4) & 127;
    src = ((size_t)bb * 16384 + p * 128 + q) * 384;
  } else {
    src = (size_t)r * 384;
  }
  float v[6];
  float s = 0.f, s2 = 0.f;
#pragma unroll
  for (int m = 0; m < 6; ++m) {
    v[m] = x[src + lane + 64 * m];
    s += v[m];
    s2 += v[m] * v[m];
  }
#pragma unroll
  for (int o2 = 1; o2 < 64; o2 <<= 1) {
    s += __shfl_xor(s, o2);
    s2 += __shfl_xor(s2, o2);
  }
  float mu = s * (1.f / 384.f);
  float var = s2 * (1.f / 384.f) - mu * mu;
  float ri = rsqrtf(var + 1e-5f);
  size_t dst = (size_t)r * 384;
#pragma unroll
  for (int m = 0; m < 6; ++m) {
    int c = lane + 64 * m;
    dst_o[dst + c] = f2bf((v[m] - mu) * ri * g[c] + b[c]);
  }
}

// ---------------- LayerNorm, bf16 input ----------------
__global__ __launch_bounds__(256)
void ln_bf16(const unsigned short* __restrict__ x, const float* __restrict__ g,
             const float* __restrict__ b, unsigned short* __restrict__ dst_o) {
  int r = blockIdx.x * 4 + (threadIdx.x >> 6);
  int lane = threadIdx.x & 63;
  size_t src = (size_t)r * 384;
  float v[6];
  float s = 0.f, s2 = 0.f;
#pragma unroll
  for (int m = 0; m < 3; ++m) {
    unsigned int u = *(const unsigned int*)&x[src + lane * 2 + 128 * m];
    v[2 * m] = bf2f((unsigned short)(u & 0xffffu));
    v[2 * m + 1] = bf2f((unsigned short)(u >> 16));
    s += v[2 * m] + v[2 * m + 1];
    s2 += v[2 * m] * v[2 * m] + v[2 * m + 1] * v[2 * m + 1];
  }
#pragma unroll
  for (int o2 = 1; o2 < 64; o2 <<= 1) {
    s += __shfl_xor(s, o2);
    s2 += __shfl_xor(s2, o2);
  }
  float mu = s * (1.f / 384.f);
  float var = s2 * (1.f / 384.f) - mu * mu;
  float ri = rsqrtf(var + 1e-5f);
#pragma unroll
  for (int m = 0; m < 3; ++m) {
    int c = lane * 2 + 128 * m;
    unsigned int lo = f2bf((v[2 * m] - mu) * ri * g[c] + b[c]);
    unsigned int hi = f2bf((v[2 * m + 1] - mu) * ri * g[c + 1] + b[c + 1]);
    *(unsigned int*)&dst_o[src + c] = lo | (hi << 16);
  }
}

// ---------------- GEMM: C(M,N) = A(M,K) * B(N,K)^T ----------------
// BM=512, BN=128, BK=64. 512 thr / 8 waves (4M x 2N), wave tile 128x64
// (acc[8][4] = 128 VGPR): per kk 12 ds_read -> 32 MFMA = 0.375 KB/MFMA —
// the VGPR-limited minimum of LDS-read bytes per MFMA (LDS-BW theory, R10).
// 2-buf LDS 160 KB (max). Protocol identical to R9 (passed): prologue
// stage+drain; per K-tile { stage(t+1); 2x[ ds_read ; barrier ; setprio MFMA ;
// barrier ] ; vmcnt(0)+barrier }. T2 both-sides swizzle (0 conflicts). m204
// XCD swizzle.
// EPI 0: bf16(acc+bias) | 1: bf16(gelu) | 2: proj scatter+resid->bf16 | 3: f32+resid
template <int EPI>
__global__ __launch_bounds__(512, 1)
void gemm10(const unsigned short* __restrict__ A, const unsigned short* __restrict__ Bw,
            const float* __restrict__ bias, int M, int N, int K, int NT,
            unsigned short* __restrict__ Obf, const void* __restrict__ resid,
            float* __restrict__ Of) {
  extern __shared__ unsigned short lds[];  // 2 x (A 512x64 + B 128x64) ushorts
  const int tid = threadIdx.x;
  const int lane = tid & 63;
  const int wid = tid >> 6;               // 0..7
  const int wm = wid >> 1, wn = wid & 1;  // wave grid 4M x 2N, wave tile 128x64
  const int li = lane & 15, lg = lane >> 4;

  // bijective XCD swizzle (m204)
  const int nwg = gridDim.x;
  const int orig = blockIdx.x;
  const int q = nwg >> 3, r = nwg & 7;
  const int xcd = orig & 7, loc = orig >> 3;
  const int wg = (xcd < r ? xcd * (q + 1) : r * (q + 1) + (xcd - r) * q) + loc;
  const int m0 = (wg / NT) * 512;
  const int n0 = (wg % NT) * 128;

  // staging: per round 512 thr x 16B = 64 rows x 128B; A 8 rounds, B 2 rounds.
  // linear LDS dest; inverse-swizzled global source col (row&7 == lane>>3).
  const int srow = wid * 8 + (lane >> 3);
  const int scol = ((lane & 7) ^ (lane >> 3)) * 8;
  const unsigned short* gA = A + (size_t)(m0 + srow) * K + scol;
  const unsigned short* gB = Bw + (size_t)(n0 + srow) * K + scol;

  const int nk = K >> 6;
  const int fswz = (li & 7) << 3;  // read-side swizzle (frag row&7 == li&7)
  f32x4 acc[8][4] = {};

  auto stage = [&](int k, unsigned short* dst) {
    unsigned short* dB = dst + 32768;
#pragma unroll
    for (int c = 0; c < 8; ++c)
      gload_lds16(gA + (size_t)(c * 64) * K + k * 64, &dst[c * 4096 + wid * 512]);
#pragma unroll
    for (int c = 0; c < 2; ++c)
      gload_lds16(gB + (size_t)(c * 64) * K + k * 64, &dB[c * 4096 + wid * 512]);
  };

  unsigned short* const buf0 = lds;
  unsigned short* const buf1 = lds + 40960;

  auto tile = [&](int t, unsigned short* cur, unsigned short* nxt) {
    if (t + 1 < nk) stage(t + 1, nxt);  // issue stage FIRST
    const unsigned short* pA = cur;
    const unsigned short* pB = cur + 32768;
#pragma unroll
    for (int kk = 0; kk < 2; ++kk) {
      bf16x8 a[8], b[4];
#pragma unroll
      for (int f = 0; f < 8; ++f)
        a[f] = *(const bf16x8*)&pA[(wm * 128 + f * 16 + li) * 64 + ((kk * 32 + lg * 8) ^ fswz)];
#pragma unroll
      for (int f = 0; f < 4; ++f)
        b[f] = *(const bf16x8*)&pB[(wn * 64 + f * 16 + li) * 64 + ((kk * 32 + lg * 8) ^ fswz)];
      __builtin_amdgcn_s_barrier();
      __builtin_amdgcn_s_setprio(1);
#pragma unroll
      for (int mf = 0; mf < 8; ++mf)
#pragma unroll
        for (int nf = 0; nf < 4; ++nf)
          acc[mf][nf] = __builtin_amdgcn_mfma_f32_16x16x32_bf16(a[mf], b[nf], acc[mf][nf], 0, 0, 0);
      __builtin_amdgcn_s_setprio(0);
      if (kk == 0) __builtin_amdgcn_s_barrier();
    }
    asm volatile("s_waitcnt vmcnt(0)" ::: "memory");  // nxt fully landed
    __builtin_amdgcn_s_barrier();
  };

  // prologue: stage K-tile 0 and DRAIN before first ds_read
  stage(0, buf0);
  asm volatile("s_waitcnt vmcnt(0)" ::: "memory");
  __builtin_amdgcn_s_barrier();

  for (int t = 0; t < nk; t += 2) {  // nk even (6 or 24); buffers static
    tile(t, buf0, buf1);
    tile(t + 1, buf1, buf0);
  }

  // epilogue: C/D layout col = lane&15, row = (lane>>4)*4 + reg
#pragma unroll
  for (int mf = 0; mf < 8; ++mf) {
#pragma unroll
    for (int r2 = 0; r2 < 4; ++r2) {
      int mrow = m0 + wm * 128 + mf * 16 + lg * 4 + r2;
      size_t orow = (size_t)mrow;
      if (EPI == 2) {
        int w = mrow >> 6, t = mrow & 63;
        int bb2 = w >> 8, wi = (w >> 4) & 15, wj = w & 15;
        int i = t >> 3, j = t & 7;
        int p = (wi * 8 + i + 4) & 127, qq = (wj * 8 + j + 4) & 127;
        orow = (size_t)bb2 * 16384 + p * 128 + qq;
      }
#pragma unroll
      for (int nf = 0; nf < 4; ++nf) {
        int col = n0 + wn * 64 + nf * 16 + li;
        float v = acc[mf][nf][r2] + bias[col];
        if (EPI == 0) {
          Obf[(size_t)mrow * N + col] = f2bf(v);
        } else if (EPI == 1) {
          float y = 1.5957691f * (v + 0.044715f * v * v * v);
          float gl = v * __builtin_amdgcn_rcpf(1.f + __expf(-y));
          Obf[(size_t)mrow * N + col] = f2bf(gl);
        } else if (EPI == 2) {
          const float* rx = (const float*)resid;
          Obf[orow * 384 + col] = f2bf(v + rx[orow * 384 + col]);
        } else {
          const unsigned short* rx = (const unsigned short*)resid;
          Of[(size_t)mrow * N + col] = v + bf2f(rx[(size_t)mrow * N + col]);
        }
      }
    }
  }
}

// ---------------- windowed attention: block = (window, head-triple); 4 waves ----------------
__global__ __launch_bounds__(256, 2)
void attn_kernel(const unsigned short* __restrict__ qkv, const float* __restrict__ btab,
                 const float* __restrict__ mask, unsigned short* __restrict__ out) {
  __shared__ unsigned short v_lds[4][64 * 40];  // V tile, row stride 40
  __shared__ unsigned short p_lds[4][64 * 72];  // P tile, row stride 72
  const int w = blockIdx.x;
  const int hi = blockIdx.y;  // 0..2
  const int tid = threadIdx.x;
  const int wid = tid >> 6, lane = tid & 63;
  const int li = lane & 15, lg = lane >> 4;
  const float* mrow = mask + (size_t)(w & 255) * 4096;
  const size_t base = (size_t)w * 64;
  const float SC = 0.17677669529663688f;  // 32^-0.5

  int h = wid * 3 + hi;
  bf16x8 aq[4], bk[4];
#pragma unroll
  for (int f = 0; f < 4; ++f) {
    size_t off = (base + f * 16 + li) * 1152 + h * 32 + lg * 8;
    aq[f] = *(const bf16x8*)&qkv[off];
    bk[f] = *(const bf16x8*)&qkv[off + 384];
  }
  f32x4 s[4][4] = {};
#pragma unroll
  for (int mf = 0; mf < 4; ++mf)
#pragma unroll
    for (int nf = 0; nf < 4; ++nf)
      s[mf][nf] = __builtin_amdgcn_mfma_f32_16x16x32_bf16(aq[mf], bk[nf], s[mf][nf], 0, 0, 0);

  {
    const unsigned short* vp = &qkv[(base + lane) * 1152 + 768 + h * 32];
    unsigned short* dp = &v_lds[wid][lane * 40];
#pragma unroll
    for (int c = 0; c < 4; ++c) *(bf16x8*)&dp[c * 8] = *(const bf16x8*)&vp[c * 8];
  }

#pragma unroll
  for (int mf = 0; mf < 4; ++mf) {
#pragma unroll
    for (int r = 0; r < 4; ++r) {
      int m = mf * 16 + lg * 4 + r;
      float mx = -1e30f;
#pragma unroll
      for (int nf = 0; nf < 4; ++nf) {
        int n = nf * 16 + li;
        int ridx = ((m >> 3) - (n >> 3) + 7) * 15 + (m & 7) - (n & 7) + 7;
        float val = s[mf][nf][r] * SC + btab[ridx * 12 + h] + mrow[m * 64 + n];
        s[mf][nf][r] = val;
        mx = fmaxf(mx, val);
      }
#pragma unroll
      for (int o2 = 1; o2 < 16; o2 <<= 1) mx = fmaxf(mx, __shfl_xor(mx, o2));
      float sum = 0.f;
#pragma unroll
      for (int nf = 0; nf < 4; ++nf) {
        float e = __expf(s[mf][nf][r] - mx);
        s[mf][nf][r] = e;
        sum += e;
      }
#pragma unroll
      for (int o2 = 1; o2 < 16; o2 <<= 1) sum += __shfl_xor(sum, o2);
      float inv = __builtin_amdgcn_rcpf(sum);
#pragma unroll
      for (int nf = 0; nf < 4; ++nf) s[mf][nf][r] *= inv;
    }
  }

#pragma unroll
  for (int mf = 0; mf < 4; ++mf)
#pragma unroll
    for (int nf = 0; nf < 4; ++nf)
#pragma unroll
      for (int r = 0; r < 4; ++r) {
        int m = mf * 16 + lg * 4 + r, n = nf * 16 + li;
        p_lds[wid][m * 72 + n] = f2bf(s[mf][nf][r]);
      }

  f32x4 o[4][2] = {};
#pragma unroll
  for (int kf = 0; kf < 2; ++kf) {
    bf16x8 bv[2];
#pragma unroll
    for (int df = 0; df < 2; ++df) {
      bf16x8 t;
#pragma unroll
      for (int e = 0; e < 8; ++e)
        t[e] = (short)v_lds[wid][(kf * 32 + lg * 8 + e) * 40 + df * 16 + li];
      bv[df] = t;
    }
#pragma unroll
    for (int mf = 0; mf < 4; ++mf) {
      bf16x8 pa = *(const bf16x8*)&p_lds[wid][(mf * 16 + li) * 72 + kf * 32 + lg * 8];
#pragma unroll
      for (int df = 0; df < 2; ++df)
        o[mf][df] = __builtin_amdgcn_mfma_f32_16x16x32_bf16(pa, bv[df], o[mf][df], 0, 0, 0);
    }
  }

#pragma unroll
  for (int mf = 0; mf < 4; ++mf)
#pragma unroll
    for (int df = 0; df < 2; ++df)
#pragma unroll
      for (int r = 0; r < 4; ++r) {
        size_t row = base + mf * 16 + lg * 4 + r;
        out[row * 384 + h * 32 + df * 16 + li] = f2bf(o[mf][df][r]);
      }
}

extern "C" void kernel_launch(void* const* d_in, const int* in_sizes, int n_in,
                              void* d_out, int out_size, void* d_ws, size_t ws_size,
                              hipStream_t stream) {
  const float* x      = (const float*)d_in[0];
  const float* qkv_w  = (const float*)d_in[1];
  const float* qkv_b  = (const float*)d_in[2];
  const float* proj_w = (const float*)d_in[3];
  const float* proj_b = (const float*)d_in[4];
  const float* rel    = (const float*)d_in[5];
  const float* g1     = (const float*)d_in[6];
  const float* b1     = (const float*)d_in[7];
  const float* g2     = (const float*)d_in[8];
  const float* b2     = (const float*)d_in[9];
  const float* fc1_w  = (const float*)d_in[10];
  const float* fc1_b  = (const float*)d_in[11];
  const float* fc2_w  = (const float*)d_in[12];
  const float* fc2_b  = (const float*)d_in[13];
  const float* mask   = (const float*)d_in[14];
  float* out = (float*)d_out;
  char* ws = (char*)d_ws;

  const int M = 131072;  // B * H * W tokens
  const int LDS_BYTES = 2 * 81920;  // 160 KB, 2-buf (A 512x64 + B 128x64)
  (void)hipFuncSetAttribute((const void*)gemm10<0>, hipFuncAttributeMaxDynamicSharedMemorySize, LDS_BYTES);
  (void)hipFuncSetAttribute((const void*)gemm10<1>, hipFuncAttributeMaxDynamicSharedMemorySize, LDS_BYTES);
  (void)hipFuncSetAttribute((const void*)gemm10<2>, hipFuncAttributeMaxDynamicSharedMemorySize, LDS_BYTES);
  (void)hipFuncSetAttribute((const void*)gemm10<3>, hipFuncAttributeMaxDynamicSharedMemorySize, LDS_BYTES);

  unsigned short* hw     = (unsigned short*)ws;
  unsigned short* qkv    = (unsigned short*)(ws + 100663296);
  unsigned short* hmid   = (unsigned short*)ws;
  unsigned short* attn_o = (unsigned short*)(ws + 402653184);
  unsigned short* ln2o   = attn_o;
  unsigned short* x1b    = (unsigned short*)(ws + 503316480);
  unsigned short* wq     = (unsigned short*)(ws + 603979776);
  unsigned short* wp     = wq + 442368;
  unsigned short* w1     = wp + 147456;
  unsigned short* w2     = w1 + 589824;

  // fused weight casts (wq|wp|w1|w2 contiguous)
  cvt_all<<<(442368 + 147456 + 589824 + 589824 + 255) / 256, 256, 0, stream>>>(
      qkv_w, 442368, proj_w, 147456, fc1_w, 589824, fc2_w, 589824, wq);

  // LN1 + shift + window partition
  ln_kernel<1><<<M / 4, 256, 0, stream>>>(x, g1, b1, hw);

  // QKV projection: grid (M/512)*(1152/128) = 256*9
  gemm10<0><<<256 * 9, 512, LDS_BYTES, stream>>>(hw, wq, qkv_b, M, 1152, 384, 9, qkv, nullptr, nullptr);

  // windowed attention (one head-triple per block.y)
  attn_kernel<<<dim3(2048, 3), 256, 0, stream>>>(qkv, rel, mask, attn_o);

  // proj + window reverse + unshift + residual(x f32) -> x1 (bf16): 256*3
  gemm10<2><<<256 * 3, 512, LDS_BYTES, stream>>>(attn_o, wp, proj_b, M, 384, 384, 3, x1b, x, nullptr);

  // LN2 (bf16 in)
  ln_bf16<<<M / 4, 256, 0, stream>>>(x1b, g2, b2, ln2o);

  // FC1 + GELU: 256*12
  gemm10<1><<<256 * 12, 512, LDS_BYTES, stream>>>(ln2o, w1, fc1_b, M, 1536, 384, 12, hmid, nullptr, nullptr);

  // FC2 + residual(x1 bf16) -> out (f32): 256*3
  gemm10<3><<<256 * 3, 512, LDS_BYTES, stream>>>(hmid, w2, fc2_b, M, 384, 1536, 3, nullptr, x1b, out);
}

// Round 11
// 1869.672 us; speedup vs baseline: 1.1427x; 1.1427x over previous
//
#include <hip/hip_runtime.h>
#include <hip/hip_bf16.h>
#include <math.h>

typedef __attribute__((ext_vector_type(4))) float f32x4;
typedef __attribute__((ext_vector_type(8))) short bf16x8;

__device__ __forceinline__ unsigned short f2bf(float f) {
  unsigned int x = __builtin_bit_cast(unsigned int, f);
  x += 0x7fffu + ((x >> 16) & 1u);
  return (unsigned short)(x >> 16);
}
__device__ __forceinline__ float bf2f(unsigned short u) {
  unsigned int x = ((unsigned int)u) << 16;
  return __builtin_bit_cast(float, x);
}

// ---------------- fused f32 -> bf16 weight casts ----------------
__global__ void cvt_all(const float* __restrict__ s0, int n0, const float* __restrict__ s1, int n1,
                        const float* __restrict__ s2, int n2, const float* __restrict__ s3, int n3,
                        unsigned short* __restrict__ d) {
  int i = blockIdx.x * 256 + threadIdx.x;
  if (i >= n0 + n1 + n2 + n3) return;
  const float* s;
  int off;
  if (i < n0) { s = s0; off = 0; }
  else if (i < n0 + n1) { s = s1; off = n0; }
  else if (i < n0 + n1 + n2) { s = s2; off = n0 + n1; }
  else { s = s3; off = n0 + n1 + n2; }
  d[i] = f2bf(s[i - off]);
}

// ---------------- LayerNorm, f32 input ----------------
// REMAP=1: window gather for LN1 output; ALSO writes xb = bf16(x) (linear) for
// proj's residual read (saves 302 MB of f32 re-read).
template <int REMAP>
__global__ __launch_bounds__(256)
void ln_kernel(const float* __restrict__ x, const float* __restrict__ g,
               const float* __restrict__ b, unsigned short* __restrict__ dst_o,
               unsigned short* __restrict__ xb) {
  int r = blockIdx.x * 4 + (threadIdx.x >> 6);
  int lane = threadIdx.x & 63;
  size_t src;
  if (REMAP) {
    int w = r >> 6, t = r & 63;
    int bb = w >> 8, wi = (w >> 4) & 15, wj = w & 15;
    int i = t >> 3, j = t & 7;
    int p = (wi * 8 + i + 4) & 127, q = (wj * 8 + j + 4) & 127;
    src = ((size_t)bb * 16384 + p * 128 + q) * 384;
  } else {
    src = (size_t)r * 384;
  }
  float v[6];
  float s = 0.f, s2 = 0.f;
#pragma unroll
  for (int m = 0; m < 6; ++m) {
    v[m] = x[src + lane + 64 * m];
    s += v[m];
    s2 += v[m] * v[m];
  }
  if (REMAP) {
#pragma unroll
    for (int m = 0; m < 6; ++m) xb[src + lane + 64 * m] = f2bf(v[m]);
  }
#pragma unroll
  for (int o2 = 1; o2 < 64; o2 <<= 1) {
    s += __shfl_xor(s, o2);
    s2 += __shfl_xor(s2, o2);
  }
  float mu = s * (1.f / 384.f);
  float var = s2 * (1.f / 384.f) - mu * mu;
  float ri = rsqrtf(var + 1e-5f);
  size_t dst = (size_t)r * 384;
#pragma unroll
  for (int m = 0; m < 6; ++m) {
    int c = lane + 64 * m;
    dst_o[dst + c] = f2bf((v[m] - mu) * ri * g[c] + b[c]);
  }
}

// ---------------- LayerNorm, bf16 input ----------------
__global__ __launch_bounds__(256)
void ln_bf16(const unsigned short* __restrict__ x, const float* __restrict__ g,
             const float* __restrict__ b, unsigned short* __restrict__ dst_o) {
  int r = blockIdx.x * 4 + (threadIdx.x >> 6);
  int lane = threadIdx.x & 63;
  size_t src = (size_t)r * 384;
  float v[6];
  float s = 0.f, s2 = 0.f;
#pragma unroll
  for (int m = 0; m < 3; ++m) {
    unsigned int u = *(const unsigned int*)&x[src + lane * 2 + 128 * m];
    v[2 * m] = bf2f((unsigned short)(u & 0xffffu));
    v[2 * m + 1] = bf2f((unsigned short)(u >> 16));
    s += v[2 * m] + v[2 * m + 1];
    s2 += v[2 * m] * v[2 * m] + v[2 * m + 1] * v[2 * m + 1];
  }
#pragma unroll
  for (int o2 = 1; o2 < 64; o2 <<= 1) {
    s += __shfl_xor(s, o2);
    s2 += __shfl_xor(s2, o2);
  }
  float mu = s * (1.f / 384.f);
  float var = s2 * (1.f / 384.f) - mu * mu;
  float ri = rsqrtf(var + 1e-5f);
#pragma unroll
  for (int m = 0; m < 3; ++m) {
    int c = lane * 2 + 128 * m;
    unsigned int lo = f2bf((v[2 * m] - mu) * ri * g[c] + b[c]);
    unsigned int hi = f2bf((v[2 * m + 1] - mu) * ri * g[c + 1] + b[c + 1]);
    *(unsigned int*)&dst_o[src + c] = lo | (hi << 16);
  }
}

// ---------------- GEMM: LDS-free, barrier-free, register-double-buffered ----------------
// C(M,N) = A(M,K) * B(N,K)^T. 256 thr / 4 waves (2M x 2N), wave tile 64x96
// (acc[4][6] = 96 VGPR). Per K-step (32): 10 x global_load_dwordx4 (16B/lane,
// 16-row x 64B segments; B is <=1.2MB L2-resident, A streamed w/ XCD locality)
// prefetching step s+1 into the alternate frag set while 24 MFMAs consume the
// current set. NO __syncthreads, NO LDS: waves run free; 2 blocks/CU (VGPR).
// Rationale: R1-R9 showed all pipes <=26% busy -> barrier/staging
// serialization, and B always L2-fits (Common-mistake #7: don't stage what
// caches). Static 2-step unroll keeps all frag indexing compile-time (rule #20).
// EPI 0: bf16(acc+bias) | 1: bf16(gelu) | 2: proj scatter + bf16resid -> bf16
// EPI 3: f32 out = acc+bias+bf16resid
template <int EPI>
__global__ __launch_bounds__(256, 2)
void gemmR(const unsigned short* __restrict__ A, const unsigned short* __restrict__ Bw,
           const float* __restrict__ bias, int M, int N, int K, int NT,
           unsigned short* __restrict__ Obf, const unsigned short* __restrict__ resid,
           float* __restrict__ Of) {
  const int tid = threadIdx.x;
  const int lane = tid & 63;
  const int wid = tid >> 6;               // 0..3
  const int wm = wid >> 1, wn = wid & 1;  // wave grid 2M x 2N
  const int li = lane & 15, lg = lane >> 4;

  // bijective XCD swizzle (m204)
  const int nwg = gridDim.x;
  const int orig = blockIdx.x;
  const int q = nwg >> 3, r = nwg & 7;
  const int xcd = orig & 7, loc = orig >> 3;
  const int wg = (xcd < r ? xcd * (q + 1) : r * (q + 1) + (xcd - r) * q) + loc;
  const int m0 = (wg / NT) * 128;
  const int n0 = (wg % NT) * 192;

  // per-lane fragment base pointers (16B contiguous per lane)
  const unsigned short* pa[4];
  const unsigned short* pb[6];
#pragma unroll
  for (int f = 0; f < 4; ++f) pa[f] = A + (size_t)(m0 + wm * 64 + f * 16 + li) * K + lg * 8;
#pragma unroll
  for (int f = 0; f < 6; ++f) pb[f] = Bw + (size_t)(n0 + wn * 96 + f * 16 + li) * K + lg * 8;

  f32x4 acc[4][6] = {};
  bf16x8 a0[4], b0[6], a1[4], b1[6];

  const int ns = K >> 5;  // K-steps of 32 (12 or 48, always even)

#pragma unroll
  for (int f = 0; f < 4; ++f) a0[f] = *(const bf16x8*)(pa[f]);
#pragma unroll
  for (int f = 0; f < 6; ++f) b0[f] = *(const bf16x8*)(pb[f]);

  for (int s = 0; s < ns; s += 2) {
    if (s + 1 < ns) {
#pragma unroll
      for (int f = 0; f < 4; ++f) a1[f] = *(const bf16x8*)(pa[f] + (s + 1) * 32);
#pragma unroll
      for (int f = 0; f < 6; ++f) b1[f] = *(const bf16x8*)(pb[f] + (s + 1) * 32);
    }
#pragma unroll
    for (int mf = 0; mf < 4; ++mf)
#pragma unroll
      for (int nf = 0; nf < 6; ++nf)
        acc[mf][nf] = __builtin_amdgcn_mfma_f32_16x16x32_bf16(a0[mf], b0[nf], acc[mf][nf], 0, 0, 0);
    if (s + 2 < ns) {
#pragma unroll
      for (int f = 0; f < 4; ++f) a0[f] = *(const bf16x8*)(pa[f] + (s + 2) * 32);
#pragma unroll
      for (int f = 0; f < 6; ++f) b0[f] = *(const bf16x8*)(pb[f] + (s + 2) * 32);
    }
#pragma unroll
    for (int mf = 0; mf < 4; ++mf)
#pragma unroll
      for (int nf = 0; nf < 6; ++nf)
        acc[mf][nf] = __builtin_amdgcn_mfma_f32_16x16x32_bf16(a1[mf], b1[nf], acc[mf][nf], 0, 0, 0);
  }

  // epilogue: C/D layout col = lane&15, row = (lane>>4)*4 + reg
#pragma unroll
  for (int mf = 0; mf < 4; ++mf) {
#pragma unroll
    for (int r2 = 0; r2 < 4; ++r2) {
      int mrow = m0 + wm * 64 + mf * 16 + lg * 4 + r2;
      size_t orow = (size_t)mrow;
      if (EPI == 2) {
        int w = mrow >> 6, t = mrow & 63;
        int bb2 = w >> 8, wi = (w >> 4) & 15, wj = w & 15;
        int i = t >> 3, j = t & 7;
        int p = (wi * 8 + i + 4) & 127, qq = (wj * 8 + j + 4) & 127;
        orow = (size_t)bb2 * 16384 + p * 128 + qq;
      }
#pragma unroll
      for (int nf = 0; nf < 6; ++nf) {
        int col = n0 + wn * 96 + nf * 16 + li;
        float v = acc[mf][nf][r2] + bias[col];
        if (EPI == 0) {
          Obf[(size_t)mrow * N + col] = f2bf(v);
        } else if (EPI == 1) {
          float y = 1.5957691f * (v + 0.044715f * v * v * v);
          float gl = v * __builtin_amdgcn_rcpf(1.f + __expf(-y));
          Obf[(size_t)mrow * N + col] = f2bf(gl);
        } else if (EPI == 2) {
          Obf[orow * 384 + col] = f2bf(v + bf2f(resid[orow * 384 + col]));
        } else {
          Of[(size_t)mrow * N + col] = v + bf2f(resid[(size_t)mrow * N + col]);
        }
      }
    }
  }
}

// ---------------- windowed attention: block = (window, head-triple); 4 waves ----------------
__global__ __launch_bounds__(256, 2)
void attn_kernel(const unsigned short* __restrict__ qkv, const float* __restrict__ btab,
                 const float* __restrict__ mask, unsigned short* __restrict__ out) {
  __shared__ unsigned short v_lds[4][64 * 40];  // V tile, row stride 40
  __shared__ unsigned short p_lds[4][64 * 72];  // P tile, row stride 72
  const int w = blockIdx.x;
  const int hi = blockIdx.y;  // 0..2
  const int tid = threadIdx.x;
  const int wid = tid >> 6, lane = tid & 63;
  const int li = lane & 15, lg = lane >> 4;
  const float* mrow = mask + (size_t)(w & 255) * 4096;
  const size_t base = (size_t)w * 64;
  const float SC = 0.17677669529663688f;  // 32^-0.5

  int h = wid * 3 + hi;
  bf16x8 aq[4], bk[4];
#pragma unroll
  for (int f = 0; f < 4; ++f) {
    size_t off = (base + f * 16 + li) * 1152 + h * 32 + lg * 8;
    aq[f] = *(const bf16x8*)&qkv[off];
    bk[f] = *(const bf16x8*)&qkv[off + 384];
  }
  f32x4 s[4][4] = {};
#pragma unroll
  for (int mf = 0; mf < 4; ++mf)
#pragma unroll
    for (int nf = 0; nf < 4; ++nf)
      s[mf][nf] = __builtin_amdgcn_mfma_f32_16x16x32_bf16(aq[mf], bk[nf], s[mf][nf], 0, 0, 0);

  {
    const unsigned short* vp = &qkv[(base + lane) * 1152 + 768 + h * 32];
    unsigned short* dp = &v_lds[wid][lane * 40];
#pragma unroll
    for (int c = 0; c < 4; ++c) *(bf16x8*)&dp[c * 8] = *(const bf16x8*)&vp[c * 8];
  }

#pragma unroll
  for (int mf = 0; mf < 4; ++mf) {
#pragma unroll
    for (int r = 0; r < 4; ++r) {
      int m = mf * 16 + lg * 4 + r;
      float mx = -1e30f;
#pragma unroll
      for (int nf = 0; nf < 4; ++nf) {
        int n = nf * 16 + li;
        int ridx = ((m >> 3) - (n >> 3) + 7) * 15 + (m & 7) - (n & 7) + 7;
        float val = s[mf][nf][r] * SC + btab[ridx * 12 + h] + mrow[m * 64 + n];
        s[mf][nf][r] = val;
        mx = fmaxf(mx, val);
      }
#pragma unroll
      for (int o2 = 1; o2 < 16; o2 <<= 1) mx = fmaxf(mx, __shfl_xor(mx, o2));
      float sum = 0.f;
#pragma unroll
      for (int nf = 0; nf < 4; ++nf) {
        float e = __expf(s[mf][nf][r] - mx);
        s[mf][nf][r] = e;
        sum += e;
      }
#pragma unroll
      for (int o2 = 1; o2 < 16; o2 <<= 1) sum += __shfl_xor(sum, o2);
      float inv = __builtin_amdgcn_rcpf(sum);
#pragma unroll
      for (int nf = 0; nf < 4; ++nf) s[mf][nf][r] *= inv;
    }
  }

#pragma unroll
  for (int mf = 0; mf < 4; ++mf)
#pragma unroll
    for (int nf = 0; nf < 4; ++nf)
#pragma unroll
      for (int r = 0; r < 4; ++r) {
        int m = mf * 16 + lg * 4 + r, n = nf * 16 + li;
        p_lds[wid][m * 72 + n] = f2bf(s[mf][nf][r]);
      }

  f32x4 o[4][2] = {};
#pragma unroll
  for (int kf = 0; kf < 2; ++kf) {
    bf16x8 bv[2];
#pragma unroll
    for (int df = 0; df < 2; ++df) {
      bf16x8 t;
#pragma unroll
      for (int e = 0; e < 8; ++e)
        t[e] = (short)v_lds[wid][(kf * 32 + lg * 8 + e) * 40 + df * 16 + li];
      bv[df] = t;
    }
#pragma unroll
    for (int mf = 0; mf < 4; ++mf) {
      bf16x8 pa = *(const bf16x8*)&p_lds[wid][(mf * 16 + li) * 72 + kf * 32 + lg * 8];
#pragma unroll
      for (int df = 0; df < 2; ++df)
        o[mf][df] = __builtin_amdgcn_mfma_f32_16x16x32_bf16(pa, bv[df], o[mf][df], 0, 0, 0);
    }
  }

#pragma unroll
  for (int mf = 0; mf < 4; ++mf)
#pragma unroll
    for (int df = 0; df < 2; ++df)
#pragma unroll
      for (int r = 0; r < 4; ++r) {
        size_t row = base + mf * 16 + lg * 4 + r;
        out[row * 384 + h * 32 + df * 16 + li] = f2bf(o[mf][df][r]);
      }
}

extern "C" void kernel_launch(void* const* d_in, const int* in_sizes, int n_in,
                              void* d_out, int out_size, void* d_ws, size_t ws_size,
                              hipStream_t stream) {
  const float* x      = (const float*)d_in[0];
  const float* qkv_w  = (const float*)d_in[1];
  const float* qkv_b  = (const float*)d_in[2];
  const float* proj_w = (const float*)d_in[3];
  const float* proj_b = (const float*)d_in[4];
  const float* rel    = (const float*)d_in[5];
  const float* g1     = (const float*)d_in[6];
  const float* b1     = (const float*)d_in[7];
  const float* g2     = (const float*)d_in[8];
  const float* b2     = (const float*)d_in[9];
  const float* fc1_w  = (const float*)d_in[10];
  const float* fc1_b  = (const float*)d_in[11];
  const float* fc2_w  = (const float*)d_in[12];
  const float* fc2_b  = (const float*)d_in[13];
  const float* mask   = (const float*)d_in[14];
  float* out = (float*)d_out;
  char* ws = (char*)d_ws;

  const int M = 131072;  // B * H * W tokens
  // workspace (lifetime-overlapped):
  //   [0, 402653184):       hw bf16 + qkv bf16; later reused as hmid bf16
  //   [402653184, +100 MB): attn_o bf16; reused as ln2o bf16
  //   [503316480, +100 MB): x1 bf16
  //   [603979776, +3.4 MB): bf16 weights (wq|wp|w1|w2)
  //   [607518720, +100 MB): xb bf16 (copy of x)   (ends 708182016 <= ws)
  unsigned short* hw     = (unsigned short*)ws;
  unsigned short* qkv    = (unsigned short*)(ws + 100663296);
  unsigned short* hmid   = (unsigned short*)ws;
  unsigned short* attn_o = (unsigned short*)(ws + 402653184);
  unsigned short* ln2o   = attn_o;
  unsigned short* x1b    = (unsigned short*)(ws + 503316480);
  unsigned short* wq     = (unsigned short*)(ws + 603979776);
  unsigned short* wp     = wq + 442368;
  unsigned short* w1     = wp + 147456;
  unsigned short* w2     = w1 + 589824;
  unsigned short* xb     = (unsigned short*)(ws + 607518720);

  // fused weight casts (wq|wp|w1|w2 contiguous)
  cvt_all<<<(442368 + 147456 + 589824 + 589824 + 255) / 256, 256, 0, stream>>>(
      qkv_w, 442368, proj_w, 147456, fc1_w, 589824, fc2_w, 589824, wq);

  // LN1 + shift + window partition (also emits xb = bf16(x))
  ln_kernel<1><<<M / 4, 256, 0, stream>>>(x, g1, b1, hw, xb);

  // QKV projection: grid (M/128)*(1152/192) = 1024*6
  gemmR<0><<<1024 * 6, 256, 0, stream>>>(hw, wq, qkv_b, M, 1152, 384, 6, qkv, nullptr, nullptr);

  // windowed attention (one head-triple per block.y)
  attn_kernel<<<dim3(2048, 3), 256, 0, stream>>>(qkv, rel, mask, attn_o);

  // proj + window reverse + unshift + residual(xb bf16) -> x1 (bf16): 1024*2
  gemmR<2><<<1024 * 2, 256, 0, stream>>>(attn_o, wp, proj_b, M, 384, 384, 2, x1b, xb, nullptr);

  // LN2 (bf16 in)
  ln_bf16<<<M / 4, 256, 0, stream>>>(x1b, g2, b2, ln2o);

  // FC1 + GELU: 1024*8
  gemmR<1><<<1024 * 8, 256, 0, stream>>>(ln2o, w1, fc1_b, M, 1536, 384, 8, hmid, nullptr, nullptr);

  // FC2 + residual(x1 bf16) -> out (f32): 1024*2
  gemmR<3><<<1024 * 2, 256, 0, stream>>>(hmid, w2, fc2_b, M, 384, 1536, 2, nullptr, x1b, out);
}

// Round 13
// 1111.342 us; speedup vs baseline: 1.9224x; 1.6824x over previous
//
#include <hip/hip_runtime.h>
#include <hip/hip_bf16.h>
#include <math.h>

typedef __attribute__((ext_vector_type(4))) float f32x4;
typedef __attribute__((ext_vector_type(8))) short bf16x8;

__device__ __forceinline__ unsigned short f2bf(float f) {
  unsigned int x = __builtin_bit_cast(unsigned int, f);
  x += 0x7fffu + ((x >> 16) & 1u);
  return (unsigned short)(x >> 16);
}
__device__ __forceinline__ float bf2f(unsigned short u) {
  unsigned int x = ((unsigned int)u) << 16;
  return __builtin_bit_cast(float, x);
}

__device__ __forceinline__ void gload_lds16(const void* g, void* l) {
  __builtin_amdgcn_global_load_lds(
      (const __attribute__((address_space(1))) unsigned int*)g,
      (__attribute__((address_space(3))) unsigned int*)l, 16, 0, 0);
}

// ---------------- fused f32 -> bf16 weight casts ----------------
__global__ void cvt_all(const float* __restrict__ s0, int n0, const float* __restrict__ s1, int n1,
                        const float* __restrict__ s2, int n2, const float* __restrict__ s3, int n3,
                        unsigned short* __restrict__ d) {
  int i = blockIdx.x * 256 + threadIdx.x;
  if (i >= n0 + n1 + n2 + n3) return;
  const float* s;
  int off;
  if (i < n0) { s = s0; off = 0; }
  else if (i < n0 + n1) { s = s1; off = n0; }
  else if (i < n0 + n1 + n2) { s = s2; off = n0 + n1; }
  else { s = s3; off = n0 + n1 + n2; }
  d[i] = f2bf(s[i - off]);
}

// ---------------- LayerNorm, f32 input (REMAP: window gather + xb emit) ----------------
template <int REMAP>
__global__ __launch_bounds__(256)
void ln_kernel(const float* __restrict__ x, const float* __restrict__ g,
               const float* __restrict__ b, unsigned short* __restrict__ dst_o,
               unsigned short* __restrict__ xb) {
  int r = blockIdx.x * 4 + (threadIdx.x >> 6);
  int lane = threadIdx.x & 63;
  size_t src;
  if (REMAP) {
    int w = r >> 6, t = r & 63;
    int bb = w >> 8, wi = (w >> 4) & 15, wj = w & 15;
    int i = t >> 3, j = t & 7;
    int p = (wi * 8 + i + 4) & 127, q = (wj * 8 + j + 4) & 127;
    src = ((size_t)bb * 16384 + p * 128 + q) * 384;
  } else {
    src = (size_t)r * 384;
  }
  float v[6];
  float s = 0.f, s2 = 0.f;
#pragma unroll
  for (int m = 0; m < 6; ++m) {
    v[m] = x[src + lane + 64 * m];
    s += v[m];
    s2 += v[m] * v[m];
  }
  if (REMAP) {
#pragma unroll
    for (int m = 0; m < 6; ++m) xb[src + lane + 64 * m] = f2bf(v[m]);
  }
#pragma unroll
  for (int o2 = 1; o2 < 64; o2 <<= 1) {
    s += __shfl_xor(s, o2);
    s2 += __shfl_xor(s2, o2);
  }
  float mu = s * (1.f / 384.f);
  float var = s2 * (1.f / 384.f) - mu * mu;
  float ri = rsqrtf(var + 1e-5f);
  size_t dst = (size_t)r * 384;
#pragma unroll
  for (int m = 0; m < 6; ++m) {
    int c = lane + 64 * m;
    dst_o[dst + c] = f2bf((v[m] - mu) * ri * g[c] + b[c]);
  }
}

// ---------------- LayerNorm, bf16 input ----------------
__global__ __launch_bounds__(256)
void ln_bf16(const unsigned short* __restrict__ x, const float* __restrict__ g,
             const float* __restrict__ b, unsigned short* __restrict__ dst_o) {
  int r = blockIdx.x * 4 + (threadIdx.x >> 6);
  int lane = threadIdx.x & 63;
  size_t src = (size_t)r * 384;
  float v[6];
  float s = 0.f, s2 = 0.f;
#pragma unroll
  for (int m = 0; m < 3; ++m) {
    unsigned int u = *(const unsigned int*)&x[src + lane * 2 + 128 * m];
    v[2 * m] = bf2f((unsigned short)(u & 0xffffu));
    v[2 * m + 1] = bf2f((unsigned short)(u >> 16));
    s += v[2 * m] + v[2 * m + 1];
    s2 += v[2 * m] * v[2 * m] + v[2 * m + 1] * v[2 * m + 1];
  }
#pragma unroll
  for (int o2 = 1; o2 < 64; o2 <<= 1) {
    s += __shfl_xor(s, o2);
    s2 += __shfl_xor(s2, o2);
  }
  float mu = s * (1.f / 384.f);
  float var = s2 * (1.f / 384.f) - mu * mu;
  float ri = rsqrtf(var + 1e-5f);
#pragma unroll
  for (int m = 0; m < 3; ++m) {
    int c = lane * 2 + 128 * m;
    unsigned int lo = f2bf((v[2 * m] - mu) * ri * g[c] + b[c]);
    unsigned int hi = f2bf((v[2 * m + 1] - mu) * ri * g[c + 1] + b[c + 1]);
    *(unsigned int*)&dst_o[src + c] = lo | (hi << 16);
  }
}

// ---------------- GEMM: C(M,N) = A(M,K) * B(N,K)^T ----------------
// R12 shape (timed 1112us total) + R6's RACE-FREE protocol. BM=256, BN=128,
// BK=32. 512 thr / 8 waves (4M x 2N, wave tile 64x64, acc[4][4]). LDS
// 2 x 24 KB -> 2 blocks/CU co-resident (doubles per-CU memory streams; the
// measured wall is per-CU stream rate, ~9 B/cy at 1 block vs ~15 at 2).
// Protocol (deterministic across R4-R7): per tile { stage(t+1) FIRST;
// ds_read cur; setprio(1) MFMA setprio(0); __syncthreads() } — the
// compiler-emitted vmcnt(0)+lgkmcnt(0) drain before the barrier is the full
// safety net (R12's hand-rolled raw-barrier variant raced across replays).
// Swizzle (64B rows): LDS[row][g] = G[row][g ^ ((row>>1)&3)], both sides;
// frag-read spread = 2-way = free (m136).
// EPI 0: bf16(acc+bias) | 1: bf16(gelu) | 2: proj scatter+bf16resid->bf16 | 3: f32+resid
template <int EPI>
__global__ __launch_bounds__(512, 4)
void gemmT(const unsigned short* __restrict__ A, const unsigned short* __restrict__ Bw,
           const float* __restrict__ bias, int M, int N, int K, int NT,
           unsigned short* __restrict__ Obf, const unsigned short* __restrict__ resid,
           float* __restrict__ Of) {
  __shared__ unsigned short lds[2 * 12288];  // per buf: A 256x32 (8192) + B 128x32 (4096)
  const int tid = threadIdx.x;
  const int lane = tid & 63;
  const int wid = tid >> 6;               // 0..7
  const int wm = wid >> 1, wn = wid & 1;  // wave grid 4M x 2N, wave tile 64x64
  const int li = lane & 15, lg = lane >> 4;

  // bijective XCD swizzle (m204)
  const int nwg = gridDim.x;
  const int orig = blockIdx.x;
  const int q = nwg >> 3, r = nwg & 7;
  const int xcd = orig & 7, loc = orig >> 3;
  const int wg = (xcd < r ? xcd * (q + 1) : r * (q + 1) + (xcd - r) * q) + loc;
  const int m0 = (wg / NT) * 256;
  const int n0 = (wg % NT) * 128;

  // staging: row = tid>>2 (0..127/round), grain = tid&3 (16B each);
  // pre-swizzled source grain = grain ^ ((row>>1)&3). A: 2 rounds; B: 1.
  const int srow = tid >> 2;
  const int scol = ((tid & 3) ^ ((srow >> 1) & 3)) * 8;
  const unsigned short* gA0 = A + (size_t)(m0 + srow) * K + scol;
  const unsigned short* gA1 = A + (size_t)(m0 + 128 + srow) * K + scol;
  const unsigned short* gB0 = Bw + (size_t)(n0 + srow) * K + scol;

  const int nk = K >> 5;                       // 12 or 48 (even)
  const int gsw = (lg ^ ((li >> 1) & 3)) * 8;  // frag-read swizzled grain
  f32x4 acc[4][4] = {};

  auto stage = [&](int k, unsigned short* buf) {
    gload_lds16(gA0 + k * 32, buf + wid * 512);
    gload_lds16(gA1 + k * 32, buf + 4096 + wid * 512);
    gload_lds16(gB0 + k * 32, buf + 8192 + wid * 512);
  };

  unsigned short* const buf0 = lds;
  unsigned short* const buf1 = lds + 12288;

  auto tile = [&](int t, unsigned short* cur, unsigned short* nxt) {
    if (t + 1 < nk) stage(t + 1, nxt);  // issue next stage first; lands during MFMA
    const unsigned short* pA = cur;
    const unsigned short* pB = cur + 8192;
    bf16x8 a[4], b[4];
#pragma unroll
    for (int f = 0; f < 4; ++f) {
      a[f] = *(const bf16x8*)&pA[(wm * 64 + f * 16 + li) * 32 + gsw];
      b[f] = *(const bf16x8*)&pB[(wn * 64 + f * 16 + li) * 32 + gsw];
    }
    __builtin_amdgcn_s_setprio(1);
#pragma unroll
    for (int mf = 0; mf < 4; ++mf)
#pragma unroll
      for (int nf = 0; nf < 4; ++nf)
        acc[mf][nf] = __builtin_amdgcn_mfma_f32_16x16x32_bf16(a[mf], b[nf], acc[mf][nf], 0, 0, 0);
    __builtin_amdgcn_s_setprio(0);
    __syncthreads();  // full drain: my ds_reads done, all waves' stage landed
  };

  // prologue: stage tile 0, full drain
  stage(0, buf0);
  __syncthreads();

  for (int t = 0; t < nk; t += 2) {
    tile(t, buf0, buf1);
    tile(t + 1, buf1, buf0);
  }

  // epilogue: C/D layout col = lane&15, row = (lane>>4)*4 + reg
#pragma unroll
  for (int mf = 0; mf < 4; ++mf) {
#pragma unroll
    for (int r2 = 0; r2 < 4; ++r2) {
      int mrow = m0 + wm * 64 + mf * 16 + lg * 4 + r2;
      size_t orow = (size_t)mrow;
      if (EPI == 2) {
        int w = mrow >> 6, t = mrow & 63;
        int bb2 = w >> 8, wi = (w >> 4) & 15, wj = w & 15;
        int i = t >> 3, j = t & 7;
        int p = (wi * 8 + i + 4) & 127, qq = (wj * 8 + j + 4) & 127;
        orow = (size_t)bb2 * 16384 + p * 128 + qq;
      }
#pragma unroll
      for (int nf = 0; nf < 4; ++nf) {
        int col = n0 + wn * 64 + nf * 16 + li;
        float v = acc[mf][nf][r2] + bias[col];
        if (EPI == 0) {
          Obf[(size_t)mrow * N + col] = f2bf(v);
        } else if (EPI == 1) {
          float y = 1.5957691f * (v + 0.044715f * v * v * v);
          float gl = v * __builtin_amdgcn_rcpf(1.f + __expf(-y));
          Obf[(size_t)mrow * N + col] = f2bf(gl);
        } else if (EPI == 2) {
          Obf[orow * 384 + col] = f2bf(v + bf2f(resid[orow * 384 + col]));
        } else {
          Of[(size_t)mrow * N + col] = v + bf2f(resid[(size_t)mrow * N + col]);
        }
      }
    }
  }
}

// ---------------- windowed attention: block = (window, head-triple); 4 waves ----------------
__global__ __launch_bounds__(256, 2)
void attn_kernel(const unsigned short* __restrict__ qkv, const float* __restrict__ btab,
                 const float* __restrict__ mask, unsigned short* __restrict__ out) {
  __shared__ unsigned short v_lds[4][64 * 40];  // V tile, row stride 40
  __shared__ unsigned short p_lds[4][64 * 72];  // P tile, row stride 72
  const int w = blockIdx.x;
  const int hi = blockIdx.y;  // 0..2
  const int tid = threadIdx.x;
  const int wid = tid >> 6, lane = tid & 63;
  const int li = lane & 15, lg = lane >> 4;
  const float* mrow = mask + (size_t)(w & 255) * 4096;
  const size_t base = (size_t)w * 64;
  const float SC = 0.17677669529663688f;  // 32^-0.5

  int h = wid * 3 + hi;
  bf16x8 aq[4], bk[4];
#pragma unroll
  for (int f = 0; f < 4; ++f) {
    size_t off = (base + f * 16 + li) * 1152 + h * 32 + lg * 8;
    aq[f] = *(const bf16x8*)&qkv[off];
    bk[f] = *(const bf16x8*)&qkv[off + 384];
  }
  f32x4 s[4][4] = {};
#pragma unroll
  for (int mf = 0; mf < 4; ++mf)
#pragma unroll
    for (int nf = 0; nf < 4; ++nf)
      s[mf][nf] = __builtin_amdgcn_mfma_f32_16x16x32_bf16(aq[mf], bk[nf], s[mf][nf], 0, 0, 0);

  {
    const unsigned short* vp = &qkv[(base + lane) * 1152 + 768 + h * 32];
    unsigned short* dp = &v_lds[wid][lane * 40];
#pragma unroll
    for (int c = 0; c < 4; ++c) *(bf16x8*)&dp[c * 8] = *(const bf16x8*)&vp[c * 8];
  }

#pragma unroll
  for (int mf = 0; mf < 4; ++mf) {
#pragma unroll
    for (int r = 0; r < 4; ++r) {
      int m = mf * 16 + lg * 4 + r;
      float mx = -1e30f;
#pragma unroll
      for (int nf = 0; nf < 4; ++nf) {
        int n = nf * 16 + li;
        int ridx = ((m >> 3) - (n >> 3) + 7) * 15 + (m & 7) - (n & 7) + 7;
        float val = s[mf][nf][r] * SC + btab[ridx * 12 + h] + mrow[m * 64 + n];
        s[mf][nf][r] = val;
        mx = fmaxf(mx, val);
      }
#pragma unroll
      for (int o2 = 1; o2 < 16; o2 <<= 1) mx = fmaxf(mx, __shfl_xor(mx, o2));
      float sum = 0.f;
#pragma unroll
      for (int nf = 0; nf < 4; ++nf) {
        float e = __expf(s[mf][nf][r] - mx);
        s[mf][nf][r] = e;
        sum += e;
      }
#pragma unroll
      for (int o2 = 1; o2 < 16; o2 <<= 1) sum += __shfl_xor(sum, o2);
      float inv = __builtin_amdgcn_rcpf(sum);
#pragma unroll
      for (int nf = 0; nf < 4; ++nf) s[mf][nf][r] *= inv;
    }
  }

#pragma unroll
  for (int mf = 0; mf < 4; ++mf)
#pragma unroll
    for (int nf = 0; nf < 4; ++nf)
#pragma unroll
      for (int r = 0; r < 4; ++r) {
        int m = mf * 16 + lg * 4 + r, n = nf * 16 + li;
        p_lds[wid][m * 72 + n] = f2bf(s[mf][nf][r]);
      }

  f32x4 o[4][2] = {};
#pragma unroll
  for (int kf = 0; kf < 2; ++kf) {
    bf16x8 bv[2];
#pragma unroll
    for (int df = 0; df < 2; ++df) {
      bf16x8 t;
#pragma unroll
      for (int e = 0; e < 8; ++e)
        t[e] = (short)v_lds[wid][(kf * 32 + lg * 8 + e) * 40 + df * 16 + li];
      bv[df] = t;
    }
#pragma unroll
    for (int mf = 0; mf < 4; ++mf) {
      bf16x8 pa = *(const bf16x8*)&p_lds[wid][(mf * 16 + li) * 72 + kf * 32 + lg * 8];
#pragma unroll
      for (int df = 0; df < 2; ++df)
        o[mf][df] = __builtin_amdgcn_mfma_f32_16x16x32_bf16(pa, bv[df], o[mf][df], 0, 0, 0);
    }
  }

#pragma unroll
  for (int mf = 0; mf < 4; ++mf)
#pragma unroll
    for (int df = 0; df < 2; ++df)
#pragma unroll
      for (int r = 0; r < 4; ++r) {
        size_t row = base + mf * 16 + lg * 4 + r;
        out[row * 384 + h * 32 + df * 16 + li] = f2bf(o[mf][df][r]);
      }
}

extern "C" void kernel_launch(void* const* d_in, const int* in_sizes, int n_in,
                              void* d_out, int out_size, void* d_ws, size_t ws_size,
                              hipStream_t stream) {
  const float* x      = (const float*)d_in[0];
  const float* qkv_w  = (const float*)d_in[1];
  const float* qkv_b  = (const float*)d_in[2];
  const float* proj_w = (const float*)d_in[3];
  const float* proj_b = (const float*)d_in[4];
  const float* rel    = (const float*)d_in[5];
  const float* g1     = (const float*)d_in[6];
  const float* b1     = (const float*)d_in[7];
  const float* g2     = (const float*)d_in[8];
  const float* b2     = (const float*)d_in[9];
  const float* fc1_w  = (const float*)d_in[10];
  const float* fc1_b  = (const float*)d_in[11];
  const float* fc2_w  = (const float*)d_in[12];
  const float* fc2_b  = (const float*)d_in[13];
  const float* mask   = (const float*)d_in[14];
  float* out = (float*)d_out;
  char* ws = (char*)d_ws;

  const int M = 131072;  // B * H * W tokens
  unsigned short* hw     = (unsigned short*)ws;
  unsigned short* qkv    = (unsigned short*)(ws + 100663296);
  unsigned short* hmid   = (unsigned short*)ws;
  unsigned short* attn_o = (unsigned short*)(ws + 402653184);
  unsigned short* ln2o   = attn_o;
  unsigned short* x1b    = (unsigned short*)(ws + 503316480);
  unsigned short* wq     = (unsigned short*)(ws + 603979776);
  unsigned short* wp     = wq + 442368;
  unsigned short* w1     = wp + 147456;
  unsigned short* w2     = w1 + 589824;
  unsigned short* xb     = (unsigned short*)(ws + 607518720);

  // fused weight casts (wq|wp|w1|w2 contiguous)
  cvt_all<<<(442368 + 147456 + 589824 + 589824 + 255) / 256, 256, 0, stream>>>(
      qkv_w, 442368, proj_w, 147456, fc1_w, 589824, fc2_w, 589824, wq);

  // LN1 + shift + window partition (also emits xb = bf16(x))
  ln_kernel<1><<<M / 4, 256, 0, stream>>>(x, g1, b1, hw, xb);

  // QKV projection: grid (M/256)*(1152/128) = 512*9
  gemmT<0><<<512 * 9, 512, 0, stream>>>(hw, wq, qkv_b, M, 1152, 384, 9, qkv, nullptr, nullptr);

  // windowed attention (one head-triple per block.y)
  attn_kernel<<<dim3(2048, 3), 256, 0, stream>>>(qkv, rel, mask, attn_o);

  // proj + window reverse + unshift + residual(xb bf16) -> x1 (bf16): 512*3
  gemmT<2><<<512 * 3, 512, 0, stream>>>(attn_o, wp, proj_b, M, 384, 384, 3, x1b, xb, nullptr);

  // LN2 (bf16 in)
  ln_bf16<<<M / 4, 256, 0, stream>>>(x1b, g2, b2, ln2o);

  // FC1 + GELU: 512*12
  gemmT<1><<<512 * 12, 512, 0, stream>>>(ln2o, w1, fc1_b, M, 1536, 384, 12, hmid, nullptr, nullptr);

  // FC2 + residual(x1 bf16) -> out (f32): 512*3
  gemmT<3><<<512 * 3, 512, 0, stream>>>(hmid, w2, fc2_b, M, 384, 1536, 3, nullptr, x1b, out);
}